// Round 1
// baseline (1122.657 us; speedup 1.0000x reference)
//
#include <hip/hip_runtime.h>
#include <stdint.h>

#define NS 100000
#define NR 200000
#define EE 1000000
#define DD 128
#define NB 50
#define NSP 2000
#define NRP 4000

typedef short bf16x8 __attribute__((ext_vector_type(8)));
typedef float f32x4 __attribute__((ext_vector_type(4)));

__device__ __forceinline__ unsigned short f2bf(float f){
  unsigned u = __float_as_uint(f);
  u = (u + 0x7FFFu + ((u >> 16) & 1u)) >> 16;
  return (unsigned short)u;
}
__device__ __forceinline__ float bf2f(unsigned short s){
  return __uint_as_float(((unsigned)s) << 16);
}
__device__ __forceinline__ unsigned packbf(float a, float b){
  return (unsigned)f2bf(a) | ((unsigned)f2bf(b) << 16);
}
__device__ __forceinline__ float bflo(unsigned p){ return __uint_as_float(p << 16); }
__device__ __forceinline__ float bfhi(unsigned p){ return __uint_as_float(p & 0xFFFF0000u); }

// ---------------- weight pre-pack into MFMA B-fragment order ----------------
// Wp[mat][ct][ks][lane][j] = W[mat][k = ks*32 + (lane>>4)*8 + j][col = ct*16 + (lane&15)]
__global__ void pack_w(const float* __restrict__ Wr, const float* __restrict__ Ws,
                       unsigned short* __restrict__ Wp){
  int g = blockIdx.x*256 + threadIdx.x;   // 4*32768 = 131072 total
  if (g >= 4*32768) return;
  int j = g & 7; int rest = g >> 3;
  int lane = rest & 63; rest >>= 6;
  int ks = rest & 7; rest >>= 3;
  int ct = rest & 7; int mat = rest >> 3;
  int k  = ks*32 + (lane >> 4)*8 + j;
  int cc = ct*16 + (lane & 15);
  const float* src = (mat < 2) ? (Wr + (size_t)mat*256*DD) : (Ws + (size_t)(mat-2)*256*DD);
  Wp[g] = f2bf(src[(size_t)k*DD + cc]);
}

// ---------------- embedding inits ----------------
__global__ __launch_bounds__(256) void init_hs(const int* __restrict__ si, const int* __restrict__ ext,
        const float* __restrict__ st, const float* __restrict__ et, unsigned short* __restrict__ hs){
  int g = blockIdx.x*256 + threadIdx.x;  // one per 2 cols; total NS*64 (exact)
  int row = g >> 6, cp = g & 63;
  float2 a = ((const float2*)(st + (size_t)si[row]*DD))[cp];
  float2 b = ((const float2*)(et + (size_t)ext[row]*DD))[cp];
  ((unsigned*)hs)[g] = packbf(a.x + b.x, a.y + b.y);
}

__global__ __launch_bounds__(256) void init_hr(const int* __restrict__ tid, const float* __restrict__ pp,
        const float* __restrict__ tt, const float* __restrict__ Wpar, const float* __restrict__ bpar,
        unsigned short* __restrict__ hr){
  int g = blockIdx.x*256 + threadIdx.x;  // NR*64 (exact)
  int row = g >> 6, cp = g & 63;
  float2 acc = ((const float2*)(tt + (size_t)tid[row]*DD))[cp];
  float2 bb = ((const float2*)bpar)[cp];
  acc.x += bb.x; acc.y += bb.y;
  const float* pr = pp + (size_t)row*8;
  #pragma unroll
  for (int p = 0; p < 8; p++){
    float w = pr[p];
    float2 wp = ((const float2*)(Wpar + p*DD))[cp];
    acc.x += w*wp.x; acc.y += w*wp.y;
  }
  ((unsigned*)hr)[g] = packbf(acc.x, acc.y);
}

// ---------------- CSR build ----------------
__global__ void hist(const int* __restrict__ er, const int* __restrict__ es,
                     int* __restrict__ cR, int* __restrict__ cS){
  int i = blockIdx.x*256 + threadIdx.x;
  if (i >= EE) return;
  atomicAdd(&cR[er[i]], 1);
  atomicAdd(&cS[es[i]], 1);
}

__global__ void scan1(const int* __restrict__ in, int n, int* __restrict__ out, int* __restrict__ bsums){
  __shared__ int lds[256];
  int t = threadIdx.x;
  int base = blockIdx.x * 2048;
  int v[8]; int s = 0;
  #pragma unroll
  for (int i = 0; i < 8; i++){
    int idx = base + t*8 + i;
    int x = (idx < n) ? in[idx] : 0;
    v[i] = s; s += x;
  }
  lds[t] = s;
  __syncthreads();
  for (int d = 1; d < 256; d <<= 1){
    int x = (t >= d) ? lds[t - d] : 0;
    __syncthreads();
    lds[t] += x;
    __syncthreads();
  }
  int pre = (t == 0) ? 0 : lds[t-1];
  if (bsums != nullptr && t == 255) bsums[blockIdx.x] = lds[255];
  #pragma unroll
  for (int i = 0; i < 8; i++){
    int idx = base + t*8 + i;
    if (idx < n) out[idx] = v[i] + pre;
  }
}

__global__ void scan3(int* __restrict__ offs, const int* __restrict__ boff, int n, int total, int* __restrict__ cur){
  int i = blockIdx.x*256 + threadIdx.x;
  if (i < n){
    int v = offs[i] + boff[i >> 11];
    offs[i] = v; cur[i] = v;
  }
  if (i == 0) offs[n] = total;
}

__global__ void scatter(const int* __restrict__ er, const int* __restrict__ es,
                        int* __restrict__ curR, int* __restrict__ curS,
                        int* __restrict__ csrR, int* __restrict__ csrS){
  int i = blockIdx.x*256 + threadIdx.x;
  if (i >= EE) return;
  int r = er[i], s = es[i];
  csrR[atomicAdd(&curR[r], 1)] = s;
  csrS[atomicAdd(&curS[s], 1)] = r;
}

// ---------------- segment-sum gather: one wave per destination row ----------------
__global__ __launch_bounds__(256) void gather(const unsigned short* __restrict__ h, const int* __restrict__ offs,
        const int* __restrict__ csr, unsigned short* __restrict__ m, int nrows){
  int wid = (blockIdx.x * 256 + threadIdx.x) >> 6;
  int lane = threadIdx.x & 63;
  if (wid >= nrows) return;
  int b = offs[wid], e = offs[wid+1];
  float a0 = 0.f, a1 = 0.f;
  for (int k = b; k < e; k++){
    int src = csr[k];
    unsigned p = *(const unsigned*)(h + (size_t)src*DD + lane*2);
    a0 += bflo(p); a1 += bfhi(p);
  }
  *(unsigned*)(m + (size_t)wid*DD + lane*2) = packbf(a0, a1);
}

// ---------------- fused concat-GEMM + bias + relu, bf16 MFMA ----------------
// C[N x 128] = relu([H | M] (N x 256) @ W (256 x 128) + b), in/out bf16, W pre-packed.
// One wave computes 32 rows x 128 cols. No LDS, no barriers. In-place safe (row-private).
__global__ __launch_bounds__(256) void relu_gemm(const unsigned short* __restrict__ H,
        const unsigned short* __restrict__ M, const unsigned short* __restrict__ Wp,
        const float* __restrict__ bias, unsigned short* __restrict__ Hout, int N)
{
  int wid = (blockIdx.x * 256 + threadIdx.x) >> 6;
  int lane = threadIdx.x & 63;
  int row0 = wid * 32;
  if (row0 >= N) return;
  int rlo = lane & 15, quad = lane >> 4;

  f32x4 acc[2][8];
  #pragma unroll
  for (int i = 0; i < 2; i++)
    #pragma unroll
    for (int j = 0; j < 8; j++){ f32x4 z = {0.f,0.f,0.f,0.f}; acc[i][j] = z; }

  #pragma unroll
  for (int ks = 0; ks < 8; ks++){
    const unsigned short* src = (ks < 4) ? H : M;
    int kloc = (ks & 3) * 32 + quad * 8;
    bf16x8 a0 = *(const bf16x8*)(src + (size_t)(row0 + rlo) * DD + kloc);
    bf16x8 a1 = *(const bf16x8*)(src + (size_t)(row0 + 16 + rlo) * DD + kloc);
    #pragma unroll
    for (int ct = 0; ct < 8; ct++){
      bf16x8 bfrag = *(const bf16x8*)(Wp + (size_t)((ct*8 + ks)*64 + lane) * 8);
      acc[0][ct] = __builtin_amdgcn_mfma_f32_16x16x32_bf16(a0, bfrag, acc[0][ct], 0, 0, 0);
      acc[1][ct] = __builtin_amdgcn_mfma_f32_16x16x32_bf16(a1, bfrag, acc[1][ct], 0, 0, 0);
    }
  }

  #pragma unroll
  for (int ct = 0; ct < 8; ct++){
    float bv = bias[ct*16 + rlo];
    #pragma unroll
    for (int rt = 0; rt < 2; rt++){
      #pragma unroll
      for (int i = 0; i < 4; i++){
        int row = row0 + rt*16 + quad*4 + i;
        float v = acc[rt][ct][i] + bv;
        v = v > 0.f ? v : 0.f;
        Hout[(size_t)row*DD + ct*16 + rlo] = f2bf(v);
      }
    }
  }
}

// ---------------- segment-mean pooling ----------------
__global__ __launch_bounds__(256) void pool(const unsigned short* __restrict__ hs,
        const unsigned short* __restrict__ hr, float* __restrict__ out){
  int b = blockIdx.x, part = blockIdx.y;
  int col = threadIdx.x & 127, half = threadIdx.x >> 7;
  const unsigned short* src; int row0, outoff; float scale;
  if (part < 8){ src = hs; row0 = b*NSP + part*250; outoff = b*256 + col; scale = 1.f/NSP; }
  else { src = hr; row0 = b*NRP + (part-8)*250; outoff = b*256 + 128 + col; scale = 1.f/NRP; }
  float acc = 0.f;
  for (int r = row0 + half; r < row0 + 250; r += 2)
    acc += bf2f(src[(size_t)r*DD + col]);
  __shared__ float red[256];
  red[threadIdx.x] = acc;
  __syncthreads();
  if (half == 0) atomicAdd(&out[outoff], (red[threadIdx.x] + red[threadIdx.x + 128]) * scale);
}

extern "C" void kernel_launch(void* const* d_in, const int* in_sizes, int n_in,
                              void* d_out, int out_size, void* d_ws, size_t ws_size,
                              hipStream_t stream)
{
  const int*   si   = (const int*)d_in[0];
  const int*   ext  = (const int*)d_in[1];
  const int*   tid  = (const int*)d_in[2];
  const float* pp   = (const float*)d_in[3];
  const int*   es   = (const int*)d_in[4];
  const int*   er   = (const int*)d_in[5];
  const float* st   = (const float*)d_in[8];
  const float* et   = (const float*)d_in[9];
  const float* tt   = (const float*)d_in[10];
  const float* Wpar = (const float*)d_in[11];
  const float* bpar = (const float*)d_in[12];
  const float* Wr   = (const float*)d_in[13];
  const float* br   = (const float*)d_in[14];
  const float* Ws   = (const float*)d_in[15];
  const float* bs   = (const float*)d_in[16];
  float* out = (float*)d_out;

  char* basep = (char*)d_ws; size_t off = 0;
  auto alloc = [&](size_t bytes)->char*{
    char* r = basep + off; off = (off + bytes + 255) & ~(size_t)255; return r;
  };
  unsigned short* h_s = (unsigned short*)alloc((size_t)NS*DD*2);
  unsigned short* h_r = (unsigned short*)alloc((size_t)NR*DD*2);
  unsigned short* msg = (unsigned short*)alloc((size_t)NR*DD*2);  // shared m_r / m_s
  unsigned short* Wp  = (unsigned short*)alloc((size_t)4*32768*2);
  int* countsR = (int*)alloc((size_t)(NR+NS)*4);   // countsS contiguous after countsR
  int* countsS = countsR + NR;
  int* offsR = (int*)alloc((size_t)(NR+1)*4);
  int* offsS = (int*)alloc((size_t)(NS+1)*4);
  int* curR  = (int*)alloc((size_t)NR*4);
  int* curS  = (int*)alloc((size_t)NS*4);
  int* bsumR = (int*)alloc(1024);
  int* boffR = (int*)alloc(1024);
  int* bsumS = (int*)alloc(1024);
  int* boffS = (int*)alloc(1024);
  int* csrR  = (int*)alloc((size_t)EE*4);
  int* csrS  = (int*)alloc((size_t)EE*4);

  hipMemsetAsync(countsR, 0, (size_t)(NR+NS)*4, stream);
  hipMemsetAsync(d_out, 0, (size_t)out_size*4, stream);

  pack_w<<<512, 256, 0, stream>>>(Wr, Ws, Wp);
  init_hs<<<NS*64/256, 256, 0, stream>>>(si, ext, st, et, h_s);
  init_hr<<<NR*64/256, 256, 0, stream>>>(tid, pp, tt, Wpar, bpar, h_r);

  hist<<<(EE+255)/256, 256, 0, stream>>>(er, es, countsR, countsS);
  scan1<<<(NR+2047)/2048, 256, 0, stream>>>(countsR, NR, offsR, bsumR);
  scan1<<<1, 256, 0, stream>>>(bsumR, (NR+2047)/2048, boffR, (int*)nullptr);
  scan3<<<(NR+255)/256, 256, 0, stream>>>(offsR, boffR, NR, EE, curR);
  scan1<<<(NS+2047)/2048, 256, 0, stream>>>(countsS, NS, offsS, bsumS);
  scan1<<<1, 256, 0, stream>>>(bsumS, (NS+2047)/2048, boffS, (int*)nullptr);
  scan3<<<(NS+255)/256, 256, 0, stream>>>(offsS, boffS, NS, EE, curS);
  scatter<<<(EE+255)/256, 256, 0, stream>>>(er, es, curR, curS, csrR, csrS);

  for (int l = 0; l < 2; l++){
    // m_r = segsum(h_s over edges by reaction); h_r = relu([h_r|m_r] @ Wr[l] + br[l])
    gather<<<NR/4, 256, 0, stream>>>(h_s, offsR, csrR, msg, NR);
    relu_gemm<<<(NR/32 + 3)/4, 256, 0, stream>>>(h_r, msg, Wp + (size_t)l*32768, br + (size_t)l*DD, h_r, NR);
    // m_s = segsum(h_r over edges by species); h_s = relu([h_s|m_s] @ Ws[l] + bs[l])
    gather<<<NS/4, 256, 0, stream>>>(h_r, offsS, csrS, msg, NS);
    relu_gemm<<<(NS/32 + 3)/4, 256, 0, stream>>>(h_s, msg, Wp + (size_t)(2+l)*32768, bs + (size_t)l*DD, h_s, NS);
  }

  pool<<<dim3(NB, 24), 256, 0, stream>>>(h_s, h_r, out);
}

// Round 2
// 756.963 us; speedup vs baseline: 1.4831x; 1.4831x over previous
//
#include <hip/hip_runtime.h>
#include <stdint.h>

#define NS 100000
#define NR 200000
#define EE 1000000
#define DD 128
#define NB 50
#define NSP 2000
#define NRP 4000
#define BSH 10
#define NBR 196   /* ceil(NR/1024) */
#define NBS 98    /* ceil(NS/1024) */
#define CHUNK 8192

typedef short bf16x8 __attribute__((ext_vector_type(8)));
typedef float f32x4 __attribute__((ext_vector_type(4)));

__device__ __forceinline__ unsigned short f2bf(float f){
  unsigned u = __float_as_uint(f);
  u = (u + 0x7FFFu + ((u >> 16) & 1u)) >> 16;
  return (unsigned short)u;
}
__device__ __forceinline__ float bf2f(unsigned short s){
  return __uint_as_float(((unsigned)s) << 16);
}
__device__ __forceinline__ unsigned packbf(float a, float b){
  return (unsigned)f2bf(a) | ((unsigned)f2bf(b) << 16);
}
__device__ __forceinline__ float bflo(unsigned p){ return __uint_as_float(p << 16); }
__device__ __forceinline__ float bfhi(unsigned p){ return __uint_as_float(p & 0xFFFF0000u); }

// ---------------- weight pre-pack into MFMA B-fragment order ----------------
__global__ void pack_w(const float* __restrict__ Wr, const float* __restrict__ Ws,
                       unsigned short* __restrict__ Wp){
  int g = blockIdx.x*256 + threadIdx.x;   // 4*32768 = 131072 total
  if (g >= 4*32768) return;
  int j = g & 7; int rest = g >> 3;
  int lane = rest & 63; rest >>= 6;
  int ks = rest & 7; rest >>= 3;
  int ct = rest & 7; int mat = rest >> 3;
  int k  = ks*32 + (lane >> 4)*8 + j;
  int cc = ct*16 + (lane & 15);
  const float* src = (mat < 2) ? (Wr + (size_t)mat*256*DD) : (Ws + (size_t)(mat-2)*256*DD);
  Wp[g] = f2bf(src[(size_t)k*DD + cc]);
}

// ---------------- embedding inits ----------------
__global__ __launch_bounds__(256) void init_hs(const int* __restrict__ si, const int* __restrict__ ext,
        const float* __restrict__ st, const float* __restrict__ et, unsigned short* __restrict__ hs){
  int g = blockIdx.x*256 + threadIdx.x;  // NS*64 (exact)
  int row = g >> 6, cp = g & 63;
  float2 a = ((const float2*)(st + (size_t)si[row]*DD))[cp];
  float2 b = ((const float2*)(et + (size_t)ext[row]*DD))[cp];
  ((unsigned*)hs)[g] = packbf(a.x + b.x, a.y + b.y);
}

__global__ __launch_bounds__(256) void init_hr(const int* __restrict__ tid, const float* __restrict__ pp,
        const float* __restrict__ tt, const float* __restrict__ Wpar, const float* __restrict__ bpar,
        unsigned short* __restrict__ hr){
  int g = blockIdx.x*256 + threadIdx.x;  // NR*64 (exact)
  int row = g >> 6, cp = g & 63;
  float2 acc = ((const float2*)(tt + (size_t)tid[row]*DD))[cp];
  float2 bb = ((const float2*)bpar)[cp];
  acc.x += bb.x; acc.y += bb.y;
  const float* pr = pp + (size_t)row*8;
  #pragma unroll
  for (int p = 0; p < 8; p++){
    float w = pr[p];
    float2 wp = ((const float2*)(Wpar + p*DD))[cp];
    acc.x += w*wp.x; acc.y += w*wp.y;
  }
  ((unsigned*)hr)[g] = packbf(acc.x, acc.y);
}

// ---------------- bucketed CSR build ----------------
// Stage 1: per-bucket histogram (196 R-buckets + 98 S-buckets of 1024 dests each)
__global__ __launch_bounds__(256) void bucket_hist(const int* __restrict__ er, const int* __restrict__ es,
                                                   int* __restrict__ gcnt){
  __shared__ int cnt[NBR + NBS];
  int t = threadIdx.x;
  for (int j = t; j < NBR + NBS; j += 256) cnt[j] = 0;
  __syncthreads();
  long i0 = (long)blockIdx.x * 2048;
  for (int j = t; j < 2048; j += 256){
    long i = i0 + j;
    if (i < EE){
      atomicAdd(&cnt[er[i] >> BSH], 1);
      atomicAdd(&cnt[NBR + (es[i] >> BSH)], 1);
    }
  }
  __syncthreads();
  for (int j = t; j < NBR + NBS; j += 256)
    if (cnt[j]) atomicAdd(&gcnt[j], cnt[j]);
}

// Stage 2: exclusive scan of bucket counts (single block)
__global__ __launch_bounds__(256) void bucket_scan(const int* __restrict__ gcnt,
        int* __restrict__ bktOffR, int* __restrict__ bktOffS,
        int* __restrict__ gCurR, int* __restrict__ gCurS){
  __shared__ int a[256];
  int t = threadIdx.x;
  int own = (t < NBR) ? gcnt[t] : 0;
  a[t] = own; __syncthreads();
  for (int d = 1; d < 256; d <<= 1){
    int x = (t >= d) ? a[t-d] : 0;
    __syncthreads(); a[t] += x; __syncthreads();
  }
  if (t < NBR){ int v = a[t] - own; bktOffR[t] = v; gCurR[t] = v; }
  if (t == 0) bktOffR[NBR] = EE;
  __syncthreads();
  own = (t < NBS) ? gcnt[NBR + t] : 0;
  a[t] = own; __syncthreads();
  for (int d = 1; d < 256; d <<= 1){
    int x = (t >= d) ? a[t-d] : 0;
    __syncthreads(); a[t] += x; __syncthreads();
  }
  if (t < NBS){ int v = a[t] - own; bktOffS[t] = v; gCurS[t] = v; }
  if (t == 0) bktOffS[NBS] = EE;
}

// Stage 3: multi-split — bin edge records into bucket regions with LDS write-combining.
// record = (dest_local << 18) | src  (dest_local < 1024, src < 2^18)
__global__ __launch_bounds__(256) void bin_edges(const int* __restrict__ er, const int* __restrict__ es,
        int* __restrict__ gCurR, int* __restrict__ gCurS,
        unsigned* __restrict__ recR, unsigned* __restrict__ recS){
  __shared__ unsigned stage[CHUNK];
  __shared__ unsigned char stageb[CHUNK];
  __shared__ int cnt[256], scn[256], pref[256], gbase[256], lcur[256];
  int t = threadIdx.x;
  int side = blockIdx.y;
  const int* dest = side ? es : er;
  const int* srca = side ? er : es;
  int* gCur = side ? gCurS : gCurR;
  unsigned* rec = side ? recS : recR;
  int nbkt = side ? NBS : NBR;
  long i0 = (long)blockIdx.x * CHUNK;
  int n = (EE - i0 < CHUNK) ? (int)(EE - i0) : CHUNK;
  cnt[t] = 0;
  __syncthreads();
  for (int j = t; j < n; j += 256)
    atomicAdd(&cnt[dest[i0 + j] >> BSH], 1);
  __syncthreads();
  scn[t] = cnt[t];
  __syncthreads();
  for (int d = 1; d < 256; d <<= 1){
    int x = (t >= d) ? scn[t-d] : 0;
    __syncthreads(); scn[t] += x; __syncthreads();
  }
  pref[t] = scn[t] - cnt[t];
  lcur[t] = scn[t] - cnt[t];
  if (t < nbkt && cnt[t] > 0) gbase[t] = atomicAdd(&gCur[t], cnt[t]);
  __syncthreads();
  for (int j = t; j < n; j += 256){
    int d = dest[i0 + j];
    int s = srca[i0 + j];
    int b = d >> BSH;
    int p = atomicAdd(&lcur[b], 1);
    stage[p] = ((unsigned)(d - (b << BSH)) << 18) | (unsigned)s;
    stageb[p] = (unsigned char)b;
  }
  __syncthreads();
  for (int e = t; e < n; e += 256){
    int b = stageb[e];
    rec[gbase[b] + (e - pref[b])] = stage[e];
  }
}

// Stage 4: per-bucket CSR finalize — local hist+scan, write offs[], scatter src into
// the bucket's contiguous CSR region (L2-local).
__global__ __launch_bounds__(256) void build_csr(const unsigned* __restrict__ recR, const unsigned* __restrict__ recS,
        const int* __restrict__ bktOffR, const int* __restrict__ bktOffS,
        int* __restrict__ csrR, int* __restrict__ csrS,
        int* __restrict__ offsR, int* __restrict__ offsS){
  __shared__ int hist[1024], pref[1024], cur[1024], ws[256];
  int t = threadIdx.x;
  int bb = blockIdx.x;
  const unsigned* rec; const int* bktOff; int* csr; int* offs; int N;
  if (bb < NBR){ rec = recR; bktOff = bktOffR; csr = csrR; offs = offsR; N = NR; }
  else { bb -= NBR; rec = recS; bktOff = bktOffS; csr = csrS; offs = offsS; N = NS; }
  int d0 = bb << BSH;
  int base = bktOff[bb], cnt_ = bktOff[bb+1] - base;
  #pragma unroll
  for (int j = 0; j < 4; j++) hist[t*4+j] = 0;
  __syncthreads();
  for (int e = t; e < cnt_; e += 256)
    atomicAdd(&hist[rec[base + e] >> 18], 1);
  __syncthreads();
  int s = 0, h[4];
  #pragma unroll
  for (int j = 0; j < 4; j++){ h[j] = hist[t*4+j]; s += h[j]; }
  ws[t] = s;
  __syncthreads();
  for (int d = 1; d < 256; d <<= 1){
    int x = (t >= d) ? ws[t-d] : 0;
    __syncthreads(); ws[t] += x; __syncthreads();
  }
  int run = ws[t] - s;
  #pragma unroll
  for (int j = 0; j < 4; j++){ pref[t*4+j] = run; cur[t*4+j] = base + run; run += h[j]; }
  __syncthreads();
  int DPB = N - d0; if (DPB > 1024) DPB = 1024;
  #pragma unroll
  for (int j = 0; j < 4; j++){
    int i = t*4 + j;
    if (i < DPB) offs[d0 + i] = base + pref[i];
  }
  if (t == 0 && d0 + DPB == N) offs[N] = EE;
  __syncthreads();
  for (int e = t; e < cnt_; e += 256){
    unsigned r = rec[base + e];
    int pos = atomicAdd(&cur[r >> 18], 1);
    csr[pos] = (int)(r & 0x3FFFFu);
  }
}

// ---------------- segment-sum gather: one wave per destination row, 4-deep MLP ----------------
__global__ __launch_bounds__(256) void gather(const unsigned short* __restrict__ h, const int* __restrict__ offs,
        const int* __restrict__ csr, unsigned short* __restrict__ m, int nrows){
  int wid = (blockIdx.x * 256 + threadIdx.x) >> 6;
  int lane = threadIdx.x & 63;
  if (wid >= nrows) return;
  int b = offs[wid], e = offs[wid+1];
  float s0=0.f,s1=0.f,t0=0.f,t1=0.f,u0=0.f,u1=0.f,v0=0.f,v1=0.f;
  int k = b;
  for (; k + 4 <= e; k += 4){
    int i0 = csr[k], i1 = csr[k+1], i2 = csr[k+2], i3 = csr[k+3];
    unsigned p0 = *(const unsigned*)(h + (size_t)i0*DD + lane*2);
    unsigned p1 = *(const unsigned*)(h + (size_t)i1*DD + lane*2);
    unsigned p2 = *(const unsigned*)(h + (size_t)i2*DD + lane*2);
    unsigned p3 = *(const unsigned*)(h + (size_t)i3*DD + lane*2);
    s0 += bflo(p0); s1 += bfhi(p0);
    t0 += bflo(p1); t1 += bfhi(p1);
    u0 += bflo(p2); u1 += bfhi(p2);
    v0 += bflo(p3); v1 += bfhi(p3);
  }
  for (; k < e; k++){
    unsigned p = *(const unsigned*)(h + (size_t)csr[k]*DD + lane*2);
    s0 += bflo(p); s1 += bfhi(p);
  }
  *(unsigned*)(m + (size_t)wid*DD + lane*2) = packbf(s0+t0+u0+v0, s1+t1+u1+v1);
}

// ---------------- fused concat-GEMM + bias + relu, bf16 MFMA ----------------
__global__ __launch_bounds__(256) void relu_gemm(const unsigned short* __restrict__ H,
        const unsigned short* __restrict__ M, const unsigned short* __restrict__ Wp,
        const float* __restrict__ bias, unsigned short* __restrict__ Hout, int N)
{
  int wid = (blockIdx.x * 256 + threadIdx.x) >> 6;
  int lane = threadIdx.x & 63;
  int row0 = wid * 32;
  if (row0 >= N) return;
  int rlo = lane & 15, quad = lane >> 4;

  f32x4 acc[2][8];
  #pragma unroll
  for (int i = 0; i < 2; i++)
    #pragma unroll
    for (int j = 0; j < 8; j++){ f32x4 z = {0.f,0.f,0.f,0.f}; acc[i][j] = z; }

  #pragma unroll
  for (int ks = 0; ks < 8; ks++){
    const unsigned short* src = (ks < 4) ? H : M;
    int kloc = (ks & 3) * 32 + quad * 8;
    bf16x8 a0 = *(const bf16x8*)(src + (size_t)(row0 + rlo) * DD + kloc);
    bf16x8 a1 = *(const bf16x8*)(src + (size_t)(row0 + 16 + rlo) * DD + kloc);
    #pragma unroll
    for (int ct = 0; ct < 8; ct++){
      bf16x8 bfrag = *(const bf16x8*)(Wp + (size_t)((ct*8 + ks)*64 + lane) * 8);
      acc[0][ct] = __builtin_amdgcn_mfma_f32_16x16x32_bf16(a0, bfrag, acc[0][ct], 0, 0, 0);
      acc[1][ct] = __builtin_amdgcn_mfma_f32_16x16x32_bf16(a1, bfrag, acc[1][ct], 0, 0, 0);
    }
  }

  #pragma unroll
  for (int ct = 0; ct < 8; ct++){
    float bv = bias[ct*16 + rlo];
    #pragma unroll
    for (int rt = 0; rt < 2; rt++){
      #pragma unroll
      for (int i = 0; i < 4; i++){
        int row = row0 + rt*16 + quad*4 + i;
        float v = acc[rt][ct][i] + bv;
        v = v > 0.f ? v : 0.f;
        Hout[(size_t)row*DD + ct*16 + rlo] = f2bf(v);
      }
    }
  }
}

// ---------------- segment-mean pooling ----------------
__global__ __launch_bounds__(256) void pool(const unsigned short* __restrict__ hs,
        const unsigned short* __restrict__ hr, float* __restrict__ out){
  int b = blockIdx.x, part = blockIdx.y;
  int col = threadIdx.x & 127, half = threadIdx.x >> 7;
  const unsigned short* src; int row0, outoff; float scale;
  if (part < 8){ src = hs; row0 = b*NSP + part*250; outoff = b*256 + col; scale = 1.f/NSP; }
  else { src = hr; row0 = b*NRP + (part-8)*250; outoff = b*256 + 128 + col; scale = 1.f/NRP; }
  float acc = 0.f;
  for (int r = row0 + half; r < row0 + 250; r += 2)
    acc += bf2f(src[(size_t)r*DD + col]);
  __shared__ float red[256];
  red[threadIdx.x] = acc;
  __syncthreads();
  if (half == 0) atomicAdd(&out[outoff], (red[threadIdx.x] + red[threadIdx.x + 128]) * scale);
}

extern "C" void kernel_launch(void* const* d_in, const int* in_sizes, int n_in,
                              void* d_out, int out_size, void* d_ws, size_t ws_size,
                              hipStream_t stream)
{
  const int*   si   = (const int*)d_in[0];
  const int*   ext  = (const int*)d_in[1];
  const int*   tid  = (const int*)d_in[2];
  const float* pp   = (const float*)d_in[3];
  const int*   es   = (const int*)d_in[4];
  const int*   er   = (const int*)d_in[5];
  const float* st   = (const float*)d_in[8];
  const float* et   = (const float*)d_in[9];
  const float* tt   = (const float*)d_in[10];
  const float* Wpar = (const float*)d_in[11];
  const float* bpar = (const float*)d_in[12];
  const float* Wr   = (const float*)d_in[13];
  const float* br   = (const float*)d_in[14];
  const float* Ws   = (const float*)d_in[15];
  const float* bs   = (const float*)d_in[16];
  float* out = (float*)d_out;

  char* basep = (char*)d_ws; size_t off = 0;
  auto alloc = [&](size_t bytes)->char*{
    char* r = basep + off; off = (off + bytes + 255) & ~(size_t)255; return r;
  };
  unsigned short* h_s = (unsigned short*)alloc((size_t)NS*DD*2);
  unsigned short* h_r = (unsigned short*)alloc((size_t)NR*DD*2);
  unsigned short* msg = (unsigned short*)alloc((size_t)NR*DD*2);  // shared m_r / m_s
  unsigned short* Wp  = (unsigned short*)alloc((size_t)4*32768*2);
  int* offsR = (int*)alloc((size_t)(NR+1)*4);
  int* offsS = (int*)alloc((size_t)(NS+1)*4);
  int* csrR  = (int*)alloc((size_t)EE*4);
  int* csrS  = (int*)alloc((size_t)EE*4);
  unsigned* recR = (unsigned*)alloc((size_t)EE*4);
  unsigned* recS = (unsigned*)alloc((size_t)EE*4);
  int* gcnt   = (int*)alloc(2048);      // NBR+NBS counters
  int* bktOffR= (int*)alloc(2048);
  int* bktOffS= (int*)alloc(2048);
  int* gCurR  = (int*)alloc(2048);
  int* gCurS  = (int*)alloc(2048);

  hipMemsetAsync(gcnt, 0, 2048, stream);
  hipMemsetAsync(d_out, 0, (size_t)out_size*4, stream);

  pack_w<<<512, 256, 0, stream>>>(Wr, Ws, Wp);
  init_hs<<<NS*64/256, 256, 0, stream>>>(si, ext, st, et, h_s);
  init_hr<<<NR*64/256, 256, 0, stream>>>(tid, pp, tt, Wpar, bpar, h_r);

  bucket_hist<<<(EE + 2047)/2048, 256, 0, stream>>>(er, es, gcnt);
  bucket_scan<<<1, 256, 0, stream>>>(gcnt, bktOffR, bktOffS, gCurR, gCurS);
  bin_edges<<<dim3((EE + CHUNK - 1)/CHUNK, 2), 256, 0, stream>>>(er, es, gCurR, gCurS, recR, recS);
  build_csr<<<NBR + NBS, 256, 0, stream>>>(recR, recS, bktOffR, bktOffS, csrR, csrS, offsR, offsS);

  for (int l = 0; l < 2; l++){
    gather<<<NR/4, 256, 0, stream>>>(h_s, offsR, csrR, msg, NR);
    relu_gemm<<<(NR/32 + 3)/4, 256, 0, stream>>>(h_r, msg, Wp + (size_t)l*32768, br + (size_t)l*DD, h_r, NR);
    gather<<<NS/4, 256, 0, stream>>>(h_r, offsS, csrS, msg, NS);
    relu_gemm<<<(NS/32 + 3)/4, 256, 0, stream>>>(h_s, msg, Wp + (size_t)(2+l)*32768, bs + (size_t)l*DD, h_s, NS);
  }

  pool<<<dim3(NB, 24), 256, 0, stream>>>(h_s, h_r, out);
}

// Round 3
// 677.852 us; speedup vs baseline: 1.6562x; 1.1167x over previous
//
#include <hip/hip_runtime.h>
#include <stdint.h>

#define NS 100000
#define NR 200000
#define EE 1000000
#define DD 128
#define NB 50
#define NSP 2000
#define NRP 4000
#define BSH 10
#define NBR 196   /* ceil(NR/1024) */
#define NBS 98    /* ceil(NS/1024) */
#define CHUNK 8192

typedef short bf16x8 __attribute__((ext_vector_type(8)));
typedef float f32x4 __attribute__((ext_vector_type(4)));
typedef unsigned u32x4 __attribute__((ext_vector_type(4)));

__device__ __forceinline__ unsigned short f2bf(float f){
  unsigned u = __float_as_uint(f);
  u = (u + 0x7FFFu + ((u >> 16) & 1u)) >> 16;
  return (unsigned short)u;
}
__device__ __forceinline__ float bf2f(unsigned short s){
  return __uint_as_float(((unsigned)s) << 16);
}
__device__ __forceinline__ unsigned packbf(float a, float b){
  return (unsigned)f2bf(a) | ((unsigned)f2bf(b) << 16);
}
__device__ __forceinline__ float bflo(unsigned p){ return __uint_as_float(p << 16); }
__device__ __forceinline__ float bfhi(unsigned p){ return __uint_as_float(p & 0xFFFF0000u); }

// ---------------- weight pre-pack into MFMA B-fragment order ----------------
__global__ void pack_w(const float* __restrict__ Wr, const float* __restrict__ Ws,
                       unsigned short* __restrict__ Wp){
  int g = blockIdx.x*256 + threadIdx.x;   // 4*32768 = 131072 total
  if (g >= 4*32768) return;
  int j = g & 7; int rest = g >> 3;
  int lane = rest & 63; rest >>= 6;
  int ks = rest & 7; rest >>= 3;
  int ct = rest & 7; int mat = rest >> 3;
  int k  = ks*32 + (lane >> 4)*8 + j;
  int cc = ct*16 + (lane & 15);
  const float* src = (mat < 2) ? (Wr + (size_t)mat*256*DD) : (Ws + (size_t)(mat-2)*256*DD);
  Wp[g] = f2bf(src[(size_t)k*DD + cc]);
}

// ---------------- fused embedding init: 16B stores, float4 reads ----------------
__global__ __launch_bounds__(256) void init_all(const int* __restrict__ si, const int* __restrict__ ext,
        const int* __restrict__ tid, const float* __restrict__ pp,
        const float* __restrict__ st, const float* __restrict__ et, const float* __restrict__ tt,
        const float* __restrict__ Wpar, const float* __restrict__ bpar,
        unsigned short* __restrict__ hs, unsigned short* __restrict__ hr){
  int g = blockIdx.x*256 + threadIdx.x;   // (NS+NR)*16 total
  int row = g >> 4, colb = (g & 15) * 8;
  if (row < NS){
    const float* a = st + (size_t)si[row]*DD + colb;
    const float* b = et + (size_t)ext[row]*DD + colb;
    float4 x0 = ((const float4*)a)[0], x1 = ((const float4*)a)[1];
    float4 y0 = ((const float4*)b)[0], y1 = ((const float4*)b)[1];
    u32x4 o;
    o.x = packbf(x0.x+y0.x, x0.y+y0.y);
    o.y = packbf(x0.z+y0.z, x0.w+y0.w);
    o.z = packbf(x1.x+y1.x, x1.y+y1.y);
    o.w = packbf(x1.z+y1.z, x1.w+y1.w);
    *(u32x4*)(hs + (size_t)row*DD + colb) = o;
  } else {
    int r = row - NS;
    const float* tb = tt + (size_t)tid[r]*DD + colb;
    float4 a0 = ((const float4*)tb)[0], a1 = ((const float4*)tb)[1];
    float4 b0 = ((const float4*)(bpar+colb))[0], b1 = ((const float4*)(bpar+colb))[1];
    a0.x += b0.x; a0.y += b0.y; a0.z += b0.z; a0.w += b0.w;
    a1.x += b1.x; a1.y += b1.y; a1.z += b1.z; a1.w += b1.w;
    const float* pr = pp + (size_t)r*8;
    float4 p0 = ((const float4*)pr)[0], p1 = ((const float4*)pr)[1];
    float w[8] = {p0.x,p0.y,p0.z,p0.w,p1.x,p1.y,p1.z,p1.w};
    #pragma unroll
    for (int p = 0; p < 8; p++){
      float4 w0 = ((const float4*)(Wpar + p*DD + colb))[0];
      float4 w1 = ((const float4*)(Wpar + p*DD + colb))[1];
      a0.x += w[p]*w0.x; a0.y += w[p]*w0.y; a0.z += w[p]*w0.z; a0.w += w[p]*w0.w;
      a1.x += w[p]*w1.x; a1.y += w[p]*w1.y; a1.z += w[p]*w1.z; a1.w += w[p]*w1.w;
    }
    u32x4 o;
    o.x = packbf(a0.x, a0.y); o.y = packbf(a0.z, a0.w);
    o.z = packbf(a1.x, a1.y); o.w = packbf(a1.z, a1.w);
    *(u32x4*)(hr + (size_t)r*DD + colb) = o;
  }
}

// ---------------- bucketed CSR build ----------------
__global__ __launch_bounds__(256) void bucket_hist(const int* __restrict__ er, const int* __restrict__ es,
                                                   int* __restrict__ gcnt){
  __shared__ int cnt[NBR + NBS];
  int t = threadIdx.x;
  for (int j = t; j < NBR + NBS; j += 256) cnt[j] = 0;
  __syncthreads();
  long i0 = (long)blockIdx.x * 2048;
  for (int j = t; j < 2048; j += 256){
    long i = i0 + j;
    if (i < EE){
      atomicAdd(&cnt[er[i] >> BSH], 1);
      atomicAdd(&cnt[NBR + (es[i] >> BSH)], 1);
    }
  }
  __syncthreads();
  for (int j = t; j < NBR + NBS; j += 256)
    if (cnt[j]) atomicAdd(&gcnt[j], cnt[j]);
}

__global__ __launch_bounds__(256) void bucket_scan(const int* __restrict__ gcnt,
        int* __restrict__ bktOffR, int* __restrict__ bktOffS,
        int* __restrict__ gCurR, int* __restrict__ gCurS){
  __shared__ int a[256];
  int t = threadIdx.x;
  int own = (t < NBR) ? gcnt[t] : 0;
  a[t] = own; __syncthreads();
  for (int d = 1; d < 256; d <<= 1){
    int x = (t >= d) ? a[t-d] : 0;
    __syncthreads(); a[t] += x; __syncthreads();
  }
  if (t < NBR){ int v = a[t] - own; bktOffR[t] = v; gCurR[t] = v; }
  if (t == 0) bktOffR[NBR] = EE;
  __syncthreads();
  own = (t < NBS) ? gcnt[NBR + t] : 0;
  a[t] = own; __syncthreads();
  for (int d = 1; d < 256; d <<= 1){
    int x = (t >= d) ? a[t-d] : 0;
    __syncthreads(); a[t] += x; __syncthreads();
  }
  if (t < NBS){ int v = a[t] - own; bktOffS[t] = v; gCurS[t] = v; }
  if (t == 0) bktOffS[NBS] = EE;
}

__global__ __launch_bounds__(256) void bin_edges(const int* __restrict__ er, const int* __restrict__ es,
        int* __restrict__ gCurR, int* __restrict__ gCurS,
        unsigned* __restrict__ recR, unsigned* __restrict__ recS){
  __shared__ unsigned stage[CHUNK];
  __shared__ unsigned char stageb[CHUNK];
  __shared__ int cnt[256], scn[256], pref[256], gbase[256], lcur[256];
  int t = threadIdx.x;
  int side = blockIdx.y;
  const int* dest = side ? es : er;
  const int* srca = side ? er : es;
  int* gCur = side ? gCurS : gCurR;
  unsigned* rec = side ? recS : recR;
  int nbkt = side ? NBS : NBR;
  long i0 = (long)blockIdx.x * CHUNK;
  int n = (EE - i0 < CHUNK) ? (int)(EE - i0) : CHUNK;
  cnt[t] = 0;
  __syncthreads();
  for (int j = t; j < n; j += 256)
    atomicAdd(&cnt[dest[i0 + j] >> BSH], 1);
  __syncthreads();
  scn[t] = cnt[t];
  __syncthreads();
  for (int d = 1; d < 256; d <<= 1){
    int x = (t >= d) ? scn[t-d] : 0;
    __syncthreads(); scn[t] += x; __syncthreads();
  }
  pref[t] = scn[t] - cnt[t];
  lcur[t] = scn[t] - cnt[t];
  if (t < nbkt && cnt[t] > 0) gbase[t] = atomicAdd(&gCur[t], cnt[t]);
  __syncthreads();
  for (int j = t; j < n; j += 256){
    int d = dest[i0 + j];
    int s = srca[i0 + j];
    int b = d >> BSH;
    int p = atomicAdd(&lcur[b], 1);
    stage[p] = ((unsigned)(d - (b << BSH)) << 18) | (unsigned)s;
    stageb[p] = (unsigned char)b;
  }
  __syncthreads();
  for (int e = t; e < n; e += 256){
    int b = stageb[e];
    rec[gbase[b] + (e - pref[b])] = stage[e];
  }
}

__global__ __launch_bounds__(256) void build_csr(const unsigned* __restrict__ recR, const unsigned* __restrict__ recS,
        const int* __restrict__ bktOffR, const int* __restrict__ bktOffS,
        int* __restrict__ csrR, int* __restrict__ csrS,
        int* __restrict__ offsR, int* __restrict__ offsS){
  __shared__ int hist[1024], pref[1024], cur[1024], ws[256];
  int t = threadIdx.x;
  int bb = blockIdx.x;
  const unsigned* rec; const int* bktOff; int* csr; int* offs; int N;
  if (bb < NBR){ rec = recR; bktOff = bktOffR; csr = csrR; offs = offsR; N = NR; }
  else { bb -= NBR; rec = recS; bktOff = bktOffS; csr = csrS; offs = offsS; N = NS; }
  int d0 = bb << BSH;
  int base = bktOff[bb], cnt_ = bktOff[bb+1] - base;
  #pragma unroll
  for (int j = 0; j < 4; j++) hist[t*4+j] = 0;
  __syncthreads();
  for (int e = t; e < cnt_; e += 256)
    atomicAdd(&hist[rec[base + e] >> 18], 1);
  __syncthreads();
  int s = 0, h[4];
  #pragma unroll
  for (int j = 0; j < 4; j++){ h[j] = hist[t*4+j]; s += h[j]; }
  ws[t] = s;
  __syncthreads();
  for (int d = 1; d < 256; d <<= 1){
    int x = (t >= d) ? ws[t-d] : 0;
    __syncthreads(); ws[t] += x; __syncthreads();
  }
  int run = ws[t] - s;
  #pragma unroll
  for (int j = 0; j < 4; j++){ pref[t*4+j] = run; cur[t*4+j] = base + run; run += h[j]; }
  __syncthreads();
  int DPB = N - d0; if (DPB > 1024) DPB = 1024;
  #pragma unroll
  for (int j = 0; j < 4; j++){
    int i = t*4 + j;
    if (i < DPB) offs[d0 + i] = base + pref[i];
  }
  if (t == 0 && d0 + DPB == N) offs[N] = EE;
  __syncthreads();
  for (int e = t; e < cnt_; e += 256){
    unsigned r = rec[base + e];
    int pos = atomicAdd(&cur[r >> 18], 1);
    csr[pos] = (int)(r & 0x3FFFFu);
  }
}

// ---------------- segment-sum gather: one wave/row, 4 quads = 4 edges in parallel ----------------
__global__ __launch_bounds__(256) void gather(const unsigned short* __restrict__ h, const int* __restrict__ offs,
        const int* __restrict__ csr, unsigned short* __restrict__ m, int nrows){
  int wid = (blockIdx.x * 256 + threadIdx.x) >> 6;
  int lane = threadIdx.x & 63;
  if (wid >= nrows) return;
  int quad = lane >> 4, sub = lane & 15;
  int b = offs[wid], e = offs[wid+1];
  float a0=0,a1=0,a2=0,a3=0,a4=0,a5=0,a6=0,a7=0;
  int k = b + quad;
  for (; k + 4 < e; k += 8){
    int s0 = csr[k], s1 = csr[k+4];
    u32x4 p = *(const u32x4*)(h + (size_t)s0*DD + sub*8);
    u32x4 q = *(const u32x4*)(h + (size_t)s1*DD + sub*8);
    a0 += bflo(p.x)+bflo(q.x); a1 += bfhi(p.x)+bfhi(q.x);
    a2 += bflo(p.y)+bflo(q.y); a3 += bfhi(p.y)+bfhi(q.y);
    a4 += bflo(p.z)+bflo(q.z); a5 += bfhi(p.z)+bfhi(q.z);
    a6 += bflo(p.w)+bflo(q.w); a7 += bfhi(p.w)+bfhi(q.w);
  }
  if (k < e){
    int s0 = csr[k];
    u32x4 p = *(const u32x4*)(h + (size_t)s0*DD + sub*8);
    a0 += bflo(p.x); a1 += bfhi(p.x);
    a2 += bflo(p.y); a3 += bfhi(p.y);
    a4 += bflo(p.z); a5 += bfhi(p.z);
    a6 += bflo(p.w); a7 += bfhi(p.w);
  }
  a0 += __shfl_xor(a0,16); a1 += __shfl_xor(a1,16);
  a2 += __shfl_xor(a2,16); a3 += __shfl_xor(a3,16);
  a4 += __shfl_xor(a4,16); a5 += __shfl_xor(a5,16);
  a6 += __shfl_xor(a6,16); a7 += __shfl_xor(a7,16);
  a0 += __shfl_xor(a0,32); a1 += __shfl_xor(a1,32);
  a2 += __shfl_xor(a2,32); a3 += __shfl_xor(a3,32);
  a4 += __shfl_xor(a4,32); a5 += __shfl_xor(a5,32);
  a6 += __shfl_xor(a6,32); a7 += __shfl_xor(a7,32);
  if (quad == 0){
    u32x4 o;
    o.x = packbf(a0,a1); o.y = packbf(a2,a3); o.z = packbf(a4,a5); o.w = packbf(a6,a7);
    *(u32x4*)(m + (size_t)wid*DD + sub*8) = o;
  }
}

// ---------------- LDS-staged concat-GEMM + bias + relu ----------------
// block = 256 thr / 4 waves / 128 rows. Stage H then M into one 34.8KB padded tile.
#define LSTR 136   /* shorts; 272B row stride: 16B-aligned, banks balanced */
__global__ __launch_bounds__(256) void relu_gemm(const unsigned short* __restrict__ H,
        const unsigned short* __restrict__ M, const unsigned short* __restrict__ Wp,
        const float* __restrict__ bias, unsigned short* __restrict__ Hout, int N)
{
  __shared__ unsigned short lA[128*LSTR];
  int t = threadIdx.x;
  int row0b = blockIdx.x * 128;
  int lane = t & 63;
  int rlo = lane & 15, quad = lane >> 4;
  int rbase = (t >> 6) * 32;

  f32x4 acc[2][8];
  #pragma unroll
  for (int i = 0; i < 2; i++)
    #pragma unroll
    for (int j = 0; j < 8; j++){ f32x4 z = {0.f,0.f,0.f,0.f}; acc[i][j] = z; }

  #pragma unroll
  for (int half = 0; half < 2; half++){
    const unsigned short* g = half ? M : H;
    if (half) __syncthreads();           // all waves done reading phase-0 tile
    #pragma unroll
    for (int r8 = 0; r8 < 8; r8++){
      int idx = r8*256 + t;
      int row = idx >> 4, cc = (idx & 15) * 8;
      bf16x8 v = {0,0,0,0,0,0,0,0};
      if (row0b + row < N) v = *(const bf16x8*)(g + (size_t)(row0b+row)*DD + cc);
      *(bf16x8*)(lA + row*LSTR + cc) = v;
    }
    __syncthreads();
    #pragma unroll
    for (int ks4 = 0; ks4 < 4; ks4++){
      int kloc = ks4*32 + quad*8;
      bf16x8 a0 = *(const bf16x8*)(lA + (rbase+rlo)*LSTR + kloc);
      bf16x8 a1 = *(const bf16x8*)(lA + (rbase+16+rlo)*LSTR + kloc);
      int ks = half*4 + ks4;
      #pragma unroll
      for (int ct = 0; ct < 8; ct++){
        bf16x8 bfrag = *(const bf16x8*)(Wp + (size_t)((ct*8 + ks)*64 + lane) * 8);
        acc[0][ct] = __builtin_amdgcn_mfma_f32_16x16x32_bf16(a0, bfrag, acc[0][ct], 0, 0, 0);
        acc[1][ct] = __builtin_amdgcn_mfma_f32_16x16x32_bf16(a1, bfrag, acc[1][ct], 0, 0, 0);
      }
    }
  }

  #pragma unroll
  for (int ct = 0; ct < 8; ct++){
    float bv = bias[ct*16 + rlo];
    #pragma unroll
    for (int rt = 0; rt < 2; rt++){
      #pragma unroll
      for (int i = 0; i < 4; i++){
        int row = row0b + rbase + rt*16 + quad*4 + i;
        if (row < N){
          float v = acc[rt][ct][i] + bv;
          v = v > 0.f ? v : 0.f;
          Hout[(size_t)row*DD + ct*16 + rlo] = f2bf(v);
        }
      }
    }
  }
}

// ---------------- segment-mean pooling: 16B loads, 2-stage reduce ----------------
__global__ __launch_bounds__(256) void pool(const unsigned short* __restrict__ hs,
        const unsigned short* __restrict__ hr, float* __restrict__ out){
  __shared__ float red[16][128];
  int b = blockIdx.x, part = blockIdx.y;   // part<4: species, else reactions (500 rows each)
  int t = threadIdx.x;
  int rg = t >> 4, sub = t & 15;
  const unsigned short* src; int row0, outoff; float scale;
  if (part < 4){ src = hs; row0 = b*NSP + part*500; outoff = b*256; scale = 1.f/NSP; }
  else { src = hr; row0 = b*NRP + (part-4)*500; outoff = b*256 + 128; scale = 1.f/NRP; }
  float a0=0,a1=0,a2=0,a3=0,a4=0,a5=0,a6=0,a7=0;
  for (int r = rg; r < 500; r += 16){
    u32x4 p = *(const u32x4*)(src + (size_t)(row0+r)*DD + sub*8);
    a0 += bflo(p.x); a1 += bfhi(p.x);
    a2 += bflo(p.y); a3 += bfhi(p.y);
    a4 += bflo(p.z); a5 += bfhi(p.z);
    a6 += bflo(p.w); a7 += bfhi(p.w);
  }
  float* rr = &red[rg][sub*8];
  rr[0]=a0; rr[1]=a1; rr[2]=a2; rr[3]=a3; rr[4]=a4; rr[5]=a5; rr[6]=a6; rr[7]=a7;
  __syncthreads();
  if (t < 128){
    float s = 0.f;
    #pragma unroll
    for (int g = 0; g < 16; g++) s += red[g][t];
    atomicAdd(&out[outoff + t], s * scale);
  }
}

extern "C" void kernel_launch(void* const* d_in, const int* in_sizes, int n_in,
                              void* d_out, int out_size, void* d_ws, size_t ws_size,
                              hipStream_t stream)
{
  const int*   si   = (const int*)d_in[0];
  const int*   ext  = (const int*)d_in[1];
  const int*   tid  = (const int*)d_in[2];
  const float* pp   = (const float*)d_in[3];
  const int*   es   = (const int*)d_in[4];
  const int*   er   = (const int*)d_in[5];
  const float* st   = (const float*)d_in[8];
  const float* et   = (const float*)d_in[9];
  const float* tt   = (const float*)d_in[10];
  const float* Wpar = (const float*)d_in[11];
  const float* bpar = (const float*)d_in[12];
  const float* Wr   = (const float*)d_in[13];
  const float* br   = (const float*)d_in[14];
  const float* Ws   = (const float*)d_in[15];
  const float* bs   = (const float*)d_in[16];
  float* out = (float*)d_out;

  char* basep = (char*)d_ws; size_t off = 0;
  auto alloc = [&](size_t bytes)->char*{
    char* r = basep + off; off = (off + bytes + 255) & ~(size_t)255; return r;
  };
  unsigned short* h_s = (unsigned short*)alloc((size_t)NS*DD*2);
  unsigned short* h_r = (unsigned short*)alloc((size_t)NR*DD*2);
  unsigned short* msg = (unsigned short*)alloc((size_t)NR*DD*2);
  unsigned short* Wp  = (unsigned short*)alloc((size_t)4*32768*2);
  int* offsR = (int*)alloc((size_t)(NR+1)*4);
  int* offsS = (int*)alloc((size_t)(NS+1)*4);
  int* csrR  = (int*)alloc((size_t)EE*4);
  int* csrS  = (int*)alloc((size_t)EE*4);
  unsigned* recR = (unsigned*)alloc((size_t)EE*4);
  unsigned* recS = (unsigned*)alloc((size_t)EE*4);
  int* gcnt   = (int*)alloc(2048);
  int* bktOffR= (int*)alloc(2048);
  int* bktOffS= (int*)alloc(2048);
  int* gCurR  = (int*)alloc(2048);
  int* gCurS  = (int*)alloc(2048);

  hipMemsetAsync(gcnt, 0, 2048, stream);
  hipMemsetAsync(d_out, 0, (size_t)out_size*4, stream);

  pack_w<<<512, 256, 0, stream>>>(Wr, Ws, Wp);
  init_all<<<(NS+NR)*16/256, 256, 0, stream>>>(si, ext, tid, pp, st, et, tt, Wpar, bpar, h_s, h_r);

  bucket_hist<<<(EE + 2047)/2048, 256, 0, stream>>>(er, es, gcnt);
  bucket_scan<<<1, 256, 0, stream>>>(gcnt, bktOffR, bktOffS, gCurR, gCurS);
  bin_edges<<<dim3((EE + CHUNK - 1)/CHUNK, 2), 256, 0, stream>>>(er, es, gCurR, gCurS, recR, recS);
  build_csr<<<NBR + NBS, 256, 0, stream>>>(recR, recS, bktOffR, bktOffS, csrR, csrS, offsR, offsS);

  for (int l = 0; l < 2; l++){
    gather<<<NR/4, 256, 0, stream>>>(h_s, offsR, csrR, msg, NR);
    relu_gemm<<<(NR + 127)/128, 256, 0, stream>>>(h_r, msg, Wp + (size_t)l*32768, br + (size_t)l*DD, h_r, NR);
    gather<<<NS/4, 256, 0, stream>>>(h_r, offsS, csrS, msg, NS);
    relu_gemm<<<(NS + 127)/128, 256, 0, stream>>>(h_s, msg, Wp + (size_t)(2+l)*32768, bs + (size_t)l*DD, h_s, NS);
  }

  pool<<<dim3(NB, 12), 256, 0, stream>>>(h_s, h_r, out);
}

// Round 4
// 550.474 us; speedup vs baseline: 2.0394x; 1.2314x over previous
//
#include <hip/hip_runtime.h>
#include <stdint.h>

#define NS 100000
#define NR 200000
#define EE 1000000
#define DD 128
#define NB 50
#define NSP 2000
#define NRP 4000
#define BSH 10
#define NBR 196   /* ceil(NR/1024) */
#define NBS 98    /* ceil(NS/1024) */
#define CHUNK 8192

typedef short bf16x8 __attribute__((ext_vector_type(8)));
typedef float f32x4 __attribute__((ext_vector_type(4)));
typedef unsigned u32x4 __attribute__((ext_vector_type(4)));

__device__ __forceinline__ unsigned short f2bf(float f){
  unsigned u = __float_as_uint(f);
  u = (u + 0x7FFFu + ((u >> 16) & 1u)) >> 16;
  return (unsigned short)u;
}
__device__ __forceinline__ float bf2f(unsigned short s){
  return __uint_as_float(((unsigned)s) << 16);
}
__device__ __forceinline__ unsigned packbf(float a, float b){
  return (unsigned)f2bf(a) | ((unsigned)f2bf(b) << 16);
}
__device__ __forceinline__ float bflo(unsigned p){ return __uint_as_float(p << 16); }
__device__ __forceinline__ float bfhi(unsigned p){ return __uint_as_float(p & 0xFFFF0000u); }

// ---------------- weight pre-pack into MFMA B-fragment order ----------------
__global__ void pack_w(const float* __restrict__ Wr, const float* __restrict__ Ws,
                       unsigned short* __restrict__ Wp){
  int g = blockIdx.x*256 + threadIdx.x;   // 4*32768 = 131072 total
  if (g >= 4*32768) return;
  int j = g & 7; int rest = g >> 3;
  int lane = rest & 63; rest >>= 6;
  int ks = rest & 7; rest >>= 3;
  int ct = rest & 7; int mat = rest >> 3;
  int k  = ks*32 + (lane >> 4)*8 + j;
  int cc = ct*16 + (lane & 15);
  const float* src = (mat < 2) ? (Wr + (size_t)mat*256*DD) : (Ws + (size_t)(mat-2)*256*DD);
  Wp[g] = f2bf(src[(size_t)k*DD + cc]);
}

// ---------------- fused embedding init: 16B stores, float4 reads ----------------
__global__ __launch_bounds__(256) void init_all(const int* __restrict__ si, const int* __restrict__ ext,
        const int* __restrict__ tid, const float* __restrict__ pp,
        const float* __restrict__ st, const float* __restrict__ et, const float* __restrict__ tt,
        const float* __restrict__ Wpar, const float* __restrict__ bpar,
        unsigned short* __restrict__ hs, unsigned short* __restrict__ hr){
  int g = blockIdx.x*256 + threadIdx.x;   // (NS+NR)*16 total
  int row = g >> 4, colb = (g & 15) * 8;
  if (row < NS){
    const float* a = st + (size_t)si[row]*DD + colb;
    const float* b = et + (size_t)ext[row]*DD + colb;
    float4 x0 = ((const float4*)a)[0], x1 = ((const float4*)a)[1];
    float4 y0 = ((const float4*)b)[0], y1 = ((const float4*)b)[1];
    u32x4 o;
    o.x = packbf(x0.x+y0.x, x0.y+y0.y);
    o.y = packbf(x0.z+y0.z, x0.w+y0.w);
    o.z = packbf(x1.x+y1.x, x1.y+y1.y);
    o.w = packbf(x1.z+y1.z, x1.w+y1.w);
    *(u32x4*)(hs + (size_t)row*DD + colb) = o;
  } else {
    int r = row - NS;
    const float* tb = tt + (size_t)tid[r]*DD + colb;
    float4 a0 = ((const float4*)tb)[0], a1 = ((const float4*)tb)[1];
    float4 b0 = ((const float4*)(bpar+colb))[0], b1 = ((const float4*)(bpar+colb))[1];
    a0.x += b0.x; a0.y += b0.y; a0.z += b0.z; a0.w += b0.w;
    a1.x += b1.x; a1.y += b1.y; a1.z += b1.z; a1.w += b1.w;
    const float* pr = pp + (size_t)r*8;
    float4 p0 = ((const float4*)pr)[0], p1 = ((const float4*)pr)[1];
    float w[8] = {p0.x,p0.y,p0.z,p0.w,p1.x,p1.y,p1.z,p1.w};
    #pragma unroll
    for (int p = 0; p < 8; p++){
      float4 w0 = ((const float4*)(Wpar + p*DD + colb))[0];
      float4 w1 = ((const float4*)(Wpar + p*DD + colb))[1];
      a0.x += w[p]*w0.x; a0.y += w[p]*w0.y; a0.z += w[p]*w0.z; a0.w += w[p]*w0.w;
      a1.x += w[p]*w1.x; a1.y += w[p]*w1.y; a1.z += w[p]*w1.z; a1.w += w[p]*w1.w;
    }
    u32x4 o;
    o.x = packbf(a0.x, a0.y); o.y = packbf(a0.z, a0.w);
    o.z = packbf(a1.x, a1.y); o.w = packbf(a1.z, a1.w);
    *(u32x4*)(hr + (size_t)r*DD + colb) = o;
  }
}

// ---------------- bucketed CSR build ----------------
__global__ __launch_bounds__(256) void bucket_hist(const int* __restrict__ er, const int* __restrict__ es,
                                                   int* __restrict__ gcnt){
  __shared__ int cnt[NBR + NBS];
  int t = threadIdx.x;
  for (int j = t; j < NBR + NBS; j += 256) cnt[j] = 0;
  __syncthreads();
  long i0 = (long)blockIdx.x * 2048;
  for (int j = t; j < 2048; j += 256){
    long i = i0 + j;
    if (i < EE){
      atomicAdd(&cnt[er[i] >> BSH], 1);
      atomicAdd(&cnt[NBR + (es[i] >> BSH)], 1);
    }
  }
  __syncthreads();
  for (int j = t; j < NBR + NBS; j += 256)
    if (cnt[j]) atomicAdd(&gcnt[j], cnt[j]);
}

__global__ __launch_bounds__(256) void bucket_scan(const int* __restrict__ gcnt,
        int* __restrict__ bktOffR, int* __restrict__ bktOffS,
        int* __restrict__ gCurR, int* __restrict__ gCurS){
  __shared__ int a[256];
  int t = threadIdx.x;
  int own = (t < NBR) ? gcnt[t] : 0;
  a[t] = own; __syncthreads();
  for (int d = 1; d < 256; d <<= 1){
    int x = (t >= d) ? a[t-d] : 0;
    __syncthreads(); a[t] += x; __syncthreads();
  }
  if (t < NBR){ int v = a[t] - own; bktOffR[t] = v; gCurR[t] = v; }
  if (t == 0) bktOffR[NBR] = EE;
  __syncthreads();
  own = (t < NBS) ? gcnt[NBR + t] : 0;
  a[t] = own; __syncthreads();
  for (int d = 1; d < 256; d <<= 1){
    int x = (t >= d) ? a[t-d] : 0;
    __syncthreads(); a[t] += x; __syncthreads();
  }
  if (t < NBS){ int v = a[t] - own; bktOffS[t] = v; gCurS[t] = v; }
  if (t == 0) bktOffS[NBS] = EE;
}

__global__ __launch_bounds__(256) void bin_edges(const int* __restrict__ er, const int* __restrict__ es,
        int* __restrict__ gCurR, int* __restrict__ gCurS,
        unsigned* __restrict__ recR, unsigned* __restrict__ recS){
  __shared__ unsigned stage[CHUNK];
  __shared__ unsigned char stageb[CHUNK];
  __shared__ int cnt[256], scn[256], pref[256], gbase[256], lcur[256];
  int t = threadIdx.x;
  int side = blockIdx.y;
  const int* dest = side ? es : er;
  const int* srca = side ? er : es;
  int* gCur = side ? gCurS : gCurR;
  unsigned* rec = side ? recS : recR;
  int nbkt = side ? NBS : NBR;
  long i0 = (long)blockIdx.x * CHUNK;
  int n = (EE - i0 < CHUNK) ? (int)(EE - i0) : CHUNK;
  cnt[t] = 0;
  __syncthreads();
  for (int j = t; j < n; j += 256)
    atomicAdd(&cnt[dest[i0 + j] >> BSH], 1);
  __syncthreads();
  scn[t] = cnt[t];
  __syncthreads();
  for (int d = 1; d < 256; d <<= 1){
    int x = (t >= d) ? scn[t-d] : 0;
    __syncthreads(); scn[t] += x; __syncthreads();
  }
  pref[t] = scn[t] - cnt[t];
  lcur[t] = scn[t] - cnt[t];
  if (t < nbkt && cnt[t] > 0) gbase[t] = atomicAdd(&gCur[t], cnt[t]);
  __syncthreads();
  for (int j = t; j < n; j += 256){
    int d = dest[i0 + j];
    int s = srca[i0 + j];
    int b = d >> BSH;
    int p = atomicAdd(&lcur[b], 1);
    stage[p] = ((unsigned)(d - (b << BSH)) << 18) | (unsigned)s;
    stageb[p] = (unsigned char)b;
  }
  __syncthreads();
  for (int e = t; e < n; e += 256){
    int b = stageb[e];
    rec[gbase[b] + (e - pref[b])] = stage[e];
  }
}

__global__ __launch_bounds__(256) void build_csr(const unsigned* __restrict__ recR, const unsigned* __restrict__ recS,
        const int* __restrict__ bktOffR, const int* __restrict__ bktOffS,
        int* __restrict__ csrR, int* __restrict__ csrS,
        int* __restrict__ offsR, int* __restrict__ offsS){
  __shared__ int hist[1024], pref[1024], cur[1024], ws[256];
  int t = threadIdx.x;
  int bb = blockIdx.x;
  const unsigned* rec; const int* bktOff; int* csr; int* offs; int N;
  if (bb < NBR){ rec = recR; bktOff = bktOffR; csr = csrR; offs = offsR; N = NR; }
  else { bb -= NBR; rec = recS; bktOff = bktOffS; csr = csrS; offs = offsS; N = NS; }
  int d0 = bb << BSH;
  int base = bktOff[bb], cnt_ = bktOff[bb+1] - base;
  #pragma unroll
  for (int j = 0; j < 4; j++) hist[t*4+j] = 0;
  __syncthreads();
  for (int e = t; e < cnt_; e += 256)
    atomicAdd(&hist[rec[base + e] >> 18], 1);
  __syncthreads();
  int s = 0, h[4];
  #pragma unroll
  for (int j = 0; j < 4; j++){ h[j] = hist[t*4+j]; s += h[j]; }
  ws[t] = s;
  __syncthreads();
  for (int d = 1; d < 256; d <<= 1){
    int x = (t >= d) ? ws[t-d] : 0;
    __syncthreads(); ws[t] += x; __syncthreads();
  }
  int run = ws[t] - s;
  #pragma unroll
  for (int j = 0; j < 4; j++){ pref[t*4+j] = run; cur[t*4+j] = base + run; run += h[j]; }
  __syncthreads();
  int DPB = N - d0; if (DPB > 1024) DPB = 1024;
  #pragma unroll
  for (int j = 0; j < 4; j++){
    int i = t*4 + j;
    if (i < DPB) offs[d0 + i] = base + pref[i];
  }
  if (t == 0 && d0 + DPB == N) offs[N] = EE;
  __syncthreads();
  for (int e = t; e < cnt_; e += 256){
    unsigned r = rec[base + e];
    int pos = atomicAdd(&cur[r >> 18], 1);
    csr[pos] = (int)(r & 0x3FFFFu);
  }
}

// ---------------- segment-sum gather: one QUAD per row (4 rows/wave, no shuffles) ----------------
__global__ __launch_bounds__(256) void gather(const unsigned short* __restrict__ h, const int* __restrict__ offs,
        const int* __restrict__ csr, unsigned short* __restrict__ m, int nrows){
  int gw = (blockIdx.x * 256 + threadIdx.x) >> 6;
  int lane = threadIdx.x & 63;
  int quad = lane >> 4, sub = lane & 15;
  int r = gw*4 + quad;
  if (r >= nrows) return;
  int b = offs[r], e = offs[r+1];
  float a0=0,a1=0,a2=0,a3=0,a4=0,a5=0,a6=0,a7=0;
  float c0=0,c1=0,c2=0,c3=0,c4=0,c5=0,c6=0,c7=0;
  int k = b;
  for (; k + 2 <= e; k += 2){
    int s0 = csr[k], s1 = csr[k+1];
    u32x4 p = *(const u32x4*)(h + (size_t)s0*DD + sub*8);
    u32x4 q = *(const u32x4*)(h + (size_t)s1*DD + sub*8);
    a0 += bflo(p.x); a1 += bfhi(p.x); a2 += bflo(p.y); a3 += bfhi(p.y);
    a4 += bflo(p.z); a5 += bfhi(p.z); a6 += bflo(p.w); a7 += bfhi(p.w);
    c0 += bflo(q.x); c1 += bfhi(q.x); c2 += bflo(q.y); c3 += bfhi(q.y);
    c4 += bflo(q.z); c5 += bfhi(q.z); c6 += bflo(q.w); c7 += bfhi(q.w);
  }
  if (k < e){
    u32x4 p = *(const u32x4*)(h + (size_t)csr[k]*DD + sub*8);
    a0 += bflo(p.x); a1 += bfhi(p.x); a2 += bflo(p.y); a3 += bfhi(p.y);
    a4 += bflo(p.z); a5 += bfhi(p.z); a6 += bflo(p.w); a7 += bfhi(p.w);
  }
  u32x4 o;
  o.x = packbf(a0+c0, a1+c1); o.y = packbf(a2+c2, a3+c3);
  o.z = packbf(a4+c4, a5+c5); o.w = packbf(a6+c6, a7+c7);
  *(u32x4*)(m + (size_t)r*DD + sub*8) = o;
}

// ---------------- persistent-B concat-GEMM + bias + relu ----------------
// Wave owns a 32-col strip; 16 B-frags live in VGPRs for the whole kernel.
// Grid-strides over 32-row tiles. No LDS, no barriers. N % 32 == 0.
__global__ __launch_bounds__(256) void relu_gemm(const unsigned short* __restrict__ H,
        const unsigned short* __restrict__ M, const unsigned short* __restrict__ Wp,
        const float* __restrict__ bias, unsigned short* __restrict__ Hout, int N)
{
  int t = threadIdx.x;
  int lane = t & 63;
  int w = t >> 6;                       // wave -> cols [w*32, w*32+32)
  int rlo = lane & 15, quad = lane >> 4;
  int ct0 = w * 2;

  bf16x8 bf[16];                        // [ks][c]
  #pragma unroll
  for (int ks = 0; ks < 8; ks++){
    bf[ks*2+0] = *(const bf16x8*)(Wp + (size_t)(((ct0+0)*8 + ks)*64 + lane) * 8);
    bf[ks*2+1] = *(const bf16x8*)(Wp + (size_t)(((ct0+1)*8 + ks)*64 + lane) * 8);
  }
  float bv0 = bias[(ct0+0)*16 + rlo];
  float bv1 = bias[(ct0+1)*16 + rlo];

  int ntiles = N >> 5;
  for (int tile = blockIdx.x; tile < ntiles; tile += gridDim.x){
    int row0 = tile * 32;
    f32x4 acc[2][2];                    // [rb][c]
    #pragma unroll
    for (int i = 0; i < 2; i++)
      #pragma unroll
      for (int j = 0; j < 2; j++){ f32x4 z = {0.f,0.f,0.f,0.f}; acc[i][j] = z; }

    #pragma unroll
    for (int ks = 0; ks < 8; ks++){
      const unsigned short* src = (ks < 4) ? H : M;
      int kloc = (ks & 3) * 32 + quad * 8;
      bf16x8 a0 = *(const bf16x8*)(src + (size_t)(row0 + rlo) * DD + kloc);
      bf16x8 a1 = *(const bf16x8*)(src + (size_t)(row0 + 16 + rlo) * DD + kloc);
      acc[0][0] = __builtin_amdgcn_mfma_f32_16x16x32_bf16(a0, bf[ks*2+0], acc[0][0], 0, 0, 0);
      acc[0][1] = __builtin_amdgcn_mfma_f32_16x16x32_bf16(a0, bf[ks*2+1], acc[0][1], 0, 0, 0);
      acc[1][0] = __builtin_amdgcn_mfma_f32_16x16x32_bf16(a1, bf[ks*2+0], acc[1][0], 0, 0, 0);
      acc[1][1] = __builtin_amdgcn_mfma_f32_16x16x32_bf16(a1, bf[ks*2+1], acc[1][1], 0, 0, 0);
    }

    #pragma unroll
    for (int rb = 0; rb < 2; rb++){
      #pragma unroll
      for (int i = 0; i < 4; i++){
        int row = row0 + rb*16 + quad*4 + i;
        float v0 = acc[rb][0][i] + bv0;
        float v1 = acc[rb][1][i] + bv1;
        v0 = v0 > 0.f ? v0 : 0.f;
        v1 = v1 > 0.f ? v1 : 0.f;
        Hout[(size_t)row*DD + (ct0+0)*16 + rlo] = f2bf(v0);
        Hout[(size_t)row*DD + (ct0+1)*16 + rlo] = f2bf(v1);
      }
    }
  }
}

// ---------------- segment-mean pooling: 16B loads, 2-stage reduce ----------------
__global__ __launch_bounds__(256) void pool(const unsigned short* __restrict__ hs,
        const unsigned short* __restrict__ hr, float* __restrict__ out){
  __shared__ float red[16][128];
  int b = blockIdx.x, part = blockIdx.y;   // part<4: species, else reactions (500 rows each)
  int t = threadIdx.x;
  int rg = t >> 4, sub = t & 15;
  const unsigned short* src; int row0, outoff; float scale;
  if (part < 4){ src = hs; row0 = b*NSP + part*500; outoff = b*256; scale = 1.f/NSP; }
  else { src = hr; row0 = b*NRP + (part-4)*500; outoff = b*256 + 128; scale = 1.f/NRP; }
  float a0=0,a1=0,a2=0,a3=0,a4=0,a5=0,a6=0,a7=0;
  for (int r = rg; r < 500; r += 16){
    u32x4 p = *(const u32x4*)(src + (size_t)(row0+r)*DD + sub*8);
    a0 += bflo(p.x); a1 += bfhi(p.x);
    a2 += bflo(p.y); a3 += bfhi(p.y);
    a4 += bflo(p.z); a5 += bfhi(p.z);
    a6 += bflo(p.w); a7 += bfhi(p.w);
  }
  float* rr = &red[rg][sub*8];
  rr[0]=a0; rr[1]=a1; rr[2]=a2; rr[3]=a3; rr[4]=a4; rr[5]=a5; rr[6]=a6; rr[7]=a7;
  __syncthreads();
  if (t < 128){
    float s = 0.f;
    #pragma unroll
    for (int g = 0; g < 16; g++) s += red[g][t];
    atomicAdd(&out[outoff + t], s * scale);
  }
}

extern "C" void kernel_launch(void* const* d_in, const int* in_sizes, int n_in,
                              void* d_out, int out_size, void* d_ws, size_t ws_size,
                              hipStream_t stream)
{
  const int*   si   = (const int*)d_in[0];
  const int*   ext  = (const int*)d_in[1];
  const int*   tid  = (const int*)d_in[2];
  const float* pp   = (const float*)d_in[3];
  const int*   es   = (const int*)d_in[4];
  const int*   er   = (const int*)d_in[5];
  const float* st   = (const float*)d_in[8];
  const float* et   = (const float*)d_in[9];
  const float* tt   = (const float*)d_in[10];
  const float* Wpar = (const float*)d_in[11];
  const float* bpar = (const float*)d_in[12];
  const float* Wr   = (const float*)d_in[13];
  const float* br   = (const float*)d_in[14];
  const float* Ws   = (const float*)d_in[15];
  const float* bs   = (const float*)d_in[16];
  float* out = (float*)d_out;

  char* basep = (char*)d_ws; size_t off = 0;
  auto alloc = [&](size_t bytes)->char*{
    char* r = basep + off; off = (off + bytes + 255) & ~(size_t)255; return r;
  };
  unsigned short* h_s = (unsigned short*)alloc((size_t)NS*DD*2);
  unsigned short* h_r = (unsigned short*)alloc((size_t)NR*DD*2);
  unsigned short* msg = (unsigned short*)alloc((size_t)NR*DD*2);
  unsigned short* Wp  = (unsigned short*)alloc((size_t)4*32768*2);
  int* offsR = (int*)alloc((size_t)(NR+1)*4);
  int* offsS = (int*)alloc((size_t)(NS+1)*4);
  int* csrR  = (int*)alloc((size_t)EE*4);
  int* csrS  = (int*)alloc((size_t)EE*4);
  unsigned* recR = (unsigned*)alloc((size_t)EE*4);
  unsigned* recS = (unsigned*)alloc((size_t)EE*4);
  int* gcnt   = (int*)alloc(2048);
  int* bktOffR= (int*)alloc(2048);
  int* bktOffS= (int*)alloc(2048);
  int* gCurR  = (int*)alloc(2048);
  int* gCurS  = (int*)alloc(2048);

  hipMemsetAsync(gcnt, 0, 2048, stream);
  hipMemsetAsync(d_out, 0, (size_t)out_size*4, stream);

  pack_w<<<512, 256, 0, stream>>>(Wr, Ws, Wp);
  init_all<<<(NS+NR)*16/256, 256, 0, stream>>>(si, ext, tid, pp, st, et, tt, Wpar, bpar, h_s, h_r);

  bucket_hist<<<(EE + 2047)/2048, 256, 0, stream>>>(er, es, gcnt);
  bucket_scan<<<1, 256, 0, stream>>>(gcnt, bktOffR, bktOffS, gCurR, gCurS);
  bin_edges<<<dim3((EE + CHUNK - 1)/CHUNK, 2), 256, 0, stream>>>(er, es, gCurR, gCurS, recR, recS);
  build_csr<<<NBR + NBS, 256, 0, stream>>>(recR, recS, bktOffR, bktOffS, csrR, csrS, offsR, offsS);

  for (int l = 0; l < 2; l++){
    gather<<<(NR + 15)/16, 256, 0, stream>>>(h_s, offsR, csrR, msg, NR);
    relu_gemm<<<1024, 256, 0, stream>>>(h_r, msg, Wp + (size_t)l*32768, br + (size_t)l*DD, h_r, NR);
    gather<<<(NS + 15)/16, 256, 0, stream>>>(h_r, offsS, csrS, msg, NS);
    relu_gemm<<<1024, 256, 0, stream>>>(h_s, msg, Wp + (size_t)(2+l)*32768, bs + (size_t)l*DD, h_s, NS);
  }

  pool<<<dim3(NB, 12), 256, 0, stream>>>(h_s, h_r, out);
}